// Round 1
// baseline (145.884 us; speedup 1.0000x reference)
//
#include <hip/hip_runtime.h>

#define BATCH 8192
#define DIM 1024
#define HEADS 8
#define HEAD_DIM 128
#define DSTATE 256

typedef __attribute__((ext_vector_type(8))) short short8v;   // 8 bf16 (4 VGPRs)
typedef __attribute__((ext_vector_type(4))) float f32x4;
typedef __attribute__((ext_vector_type(4))) unsigned short ushort4v;

__device__ __forceinline__ unsigned short f2bf(float x) {
  unsigned int u = __builtin_bit_cast(unsigned int, x);
  unsigned int r = u + 0x7FFFu + ((u >> 16) & 1u);   // RNE
  return (unsigned short)(r >> 16);
}
__device__ __forceinline__ float bf2f(unsigned short h) {
  unsigned int u = ((unsigned int)h) << 16;
  return __builtin_bit_cast(float, u);
}

// ---------- precompute: A_bar (f32) and coef=(A_bar-1)/A ----------
__global__ void pc_params(const float* __restrict__ logdt,
                          const float* __restrict__ arelog,
                          const float* __restrict__ aim,
                          float* __restrict__ abr, float* __restrict__ abi,
                          float* __restrict__ cre, float* __restrict__ cim) {
  int i = blockIdx.x * 256 + threadIdx.x;            // 2048 = H*N
  float ld = logdt[i];
  float dt = log1pf(expf(ld));                       // softplus
  float Ar = -expf(arelog[i]);
  float Ai = aim[i];
  float e  = expf(dt * Ar);
  float th = dt * Ai;
  float Abr = e * cosf(th), Abi = e * sinf(th);
  abr[i] = Abr; abi[i] = Abi;
  float den = Ar * Ar + Ai * Ai;
  float br = Abr - 1.0f;
  cre[i] = (br * Ar + Abi * Ai) / den;
  cim[i] = (Abi * Ar - br * Ai) / den;
}

// ---------- W1 = coef * B  (bf16, layout (H,N,P)) ----------
__global__ void pc_w1(const float* __restrict__ Bre, const float* __restrict__ Bim,
                      const float* __restrict__ cre, const float* __restrict__ cim,
                      unsigned short* __restrict__ w1re, unsigned short* __restrict__ w1im) {
  int i = blockIdx.x * 256 + threadIdx.x;            // 262144 = H*N*P
  int hn = i >> 7;
  float cr = cre[hn], ci = cim[hn];
  float br = Bre[i], bi = Bim[i];
  w1re[i] = f2bf(cr * br - ci * bi);
  w1im[i] = f2bf(cr * bi + ci * br);
}

// ---------- W2 = C_re, -C_im  (bf16, layout (H,P,N)) ----------
__global__ void pc_w2(const float* __restrict__ Cre, const float* __restrict__ Cim,
                      unsigned short* __restrict__ w2re, unsigned short* __restrict__ w2mi) {
  int i = blockIdx.x * 256 + threadIdx.x;            // 262144 = H*P*N
  w2re[i] = f2bf(Cre[i]);
  w2mi[i] = f2bf(-Cim[i]);
}

// ---------- RMSNorm -> x_hat bf16 (one wave per row) ----------
__global__ __launch_bounds__(256) void rms_k(const float* __restrict__ xt,
                                             const float* __restrict__ w,
                                             unsigned short* __restrict__ xbf) {
  int wid = threadIdx.x >> 6, lane = threadIdx.x & 63;
  int row = blockIdx.x * 4 + wid;
  const float* xr = xt + (long)row * DIM;
  f32x4 v[4];
  float ssq = 0.f;
  #pragma unroll
  for (int c = 0; c < 4; ++c) {
    v[c] = *(const f32x4*)(xr + c * 256 + lane * 4);
    ssq += v[c][0]*v[c][0] + v[c][1]*v[c][1] + v[c][2]*v[c][2] + v[c][3]*v[c][3];
  }
  #pragma unroll
  for (int m = 1; m < 64; m <<= 1) ssq += __shfl_xor(ssq, m, 64);
  float sc = rsqrtf(ssq * (1.0f / DIM) + 1e-4f);
  unsigned short* orow = xbf + (long)row * DIM;
  #pragma unroll
  for (int c = 0; c < 4; ++c) {
    f32x4 w4 = *(const f32x4*)(w + c * 256 + lane * 4);
    ushort4v o;
    o[0] = f2bf(v[c][0] * sc * w4[0]);
    o[1] = f2bf(v[c][1] * sc * w4[1]);
    o[2] = f2bf(v[c][2] * sc * w4[2]);
    o[3] = f2bf(v[c][3] * sc * w4[3]);
    *(ushort4v*)(orow + c * 256 + lane * 4) = o;
  }
}

// ---------- main fused kernel ----------
// Grid: 512 blocks (64 row-tiles x 8 heads), 256 threads = 4 waves.
// Each wave owns 32 batch rows (2 b-tiles of 16) of one head. No barriers.
// GEMM1 swapped: D1[n][b] = W1[n][p] * xhat^T[p][b]   (A=W1 natural, B=x rows)
// GEMM2 swapped: D2[p][b] = [Cre|-Cim][p][n] * ns^T[n][b]
__global__ __launch_bounds__(256) void s5_main(
    const unsigned short* __restrict__ xbf,
    const unsigned short* __restrict__ w1re, const unsigned short* __restrict__ w1im,
    const unsigned short* __restrict__ w2re, const unsigned short* __restrict__ w2mi,
    const float* __restrict__ abr, const float* __restrict__ abi,
    const float* __restrict__ sre, const float* __restrict__ sim,
    const float* __restrict__ xt, const float* __restrict__ dvec,
    float* __restrict__ out, float* __restrict__ nsre, float* __restrict__ nsim) {
  __shared__ float lds[8192];                        // 32KB: 4 waves x 2KB f32
  const int tid = threadIdx.x;
  const int wid = tid >> 6, lane = tid & 63;
  const int g = lane >> 4, bl = lane & 15;
  const int h = blockIdx.x & 7;
  const int rowbase = (blockIdx.x >> 3) * 128 + wid * 32;
  float* mylds = lds + wid * 2048;
  const int swz = (bl & 7) << 2;                     // XOR swizzle, keeps 16B align

  // x_hat B-fragments: 8 contiguous bf16 per lane, row = batch b (col of B)
  short8v xf[2][4];
  #pragma unroll
  for (int bt = 0; bt < 2; ++bt) {
    const unsigned short* xrow = xbf + (rowbase + bt * 16 + bl) * DIM + h * HEAD_DIM;
    #pragma unroll
    for (int ks = 0; ks < 4; ++ks)
      xf[bt][ks] = *(const short8v*)(xrow + ks * 32 + g * 8);
  }

  f32x4 acc[8][2];
  #pragma unroll
  for (int pt = 0; pt < 8; ++pt) {
    f32x4 z = {0.f, 0.f, 0.f, 0.f};
    acc[pt][0] = z; acc[pt][1] = z;
  }

  for (int kk = 0; kk < 8; ++kk) {                   // 32 states per iteration
    #pragma unroll
    for (int t = 0; t < 2; ++t) {
      const int nt = kk * 2 + t;
      const unsigned short* w1b  = w1re + (h * DSTATE + nt * 16 + bl) * HEAD_DIM + g * 8;
      const unsigned short* w1bi = w1im + (h * DSTATE + nt * 16 + bl) * HEAD_DIM + g * 8;
      short8v ar0 = *(const short8v*)(w1b);
      short8v ar1 = *(const short8v*)(w1b + 32);
      short8v ar2 = *(const short8v*)(w1b + 64);
      short8v ar3 = *(const short8v*)(w1b + 96);
      short8v ai0 = *(const short8v*)(w1bi);
      short8v ai1 = *(const short8v*)(w1bi + 32);
      short8v ai2 = *(const short8v*)(w1bi + 64);
      short8v ai3 = *(const short8v*)(w1bi + 96);
      const int nidx = nt * 16 + g * 4;
      const f32x4 Ar = *(const f32x4*)(abr + h * DSTATE + nidx);
      const f32x4 Ai = *(const f32x4*)(abi + h * DSTATE + nidx);
      #pragma unroll
      for (int bt = 0; bt < 2; ++bt) {
        f32x4 dr = {0.f, 0.f, 0.f, 0.f};
        f32x4 di = {0.f, 0.f, 0.f, 0.f};
        dr = __builtin_amdgcn_mfma_f32_16x16x32_bf16(ar0, xf[bt][0], dr, 0, 0, 0);
        dr = __builtin_amdgcn_mfma_f32_16x16x32_bf16(ar1, xf[bt][1], dr, 0, 0, 0);
        dr = __builtin_amdgcn_mfma_f32_16x16x32_bf16(ar2, xf[bt][2], dr, 0, 0, 0);
        dr = __builtin_amdgcn_mfma_f32_16x16x32_bf16(ar3, xf[bt][3], dr, 0, 0, 0);
        di = __builtin_amdgcn_mfma_f32_16x16x32_bf16(ai0, xf[bt][0], di, 0, 0, 0);
        di = __builtin_amdgcn_mfma_f32_16x16x32_bf16(ai1, xf[bt][1], di, 0, 0, 0);
        di = __builtin_amdgcn_mfma_f32_16x16x32_bf16(ai2, xf[bt][2], di, 0, 0, 0);
        di = __builtin_amdgcn_mfma_f32_16x16x32_bf16(ai3, xf[bt][3], di, 0, 0, 0);
        // elementwise complex recurrence: ns = A_bar*state + Bx
        const int b = rowbase + bt * 16 + bl;
        const int so = (b * HEADS + h) * DSTATE + nidx;
        const f32x4 sr4 = *(const f32x4*)(sre + so);
        const f32x4 si4 = *(const f32x4*)(sim + so);
        f32x4 nr, ni;
        #pragma unroll
        for (int r = 0; r < 4; ++r) {
          nr[r] = fmaf(Ar[r], sr4[r], fmaf(-Ai[r], si4[r], dr[r]));
          ni[r] = fmaf(Ar[r], si4[r], fmaf(Ai[r], sr4[r], di[r]));
        }
        *(f32x4*)(nsre + so) = nr;
        *(f32x4*)(nsim + so) = ni;
        // stash in per-wave LDS chunk for the lane-transpose to GEMM2 B-frags
        float* lp = mylds + bt * 1024 + bl * 32 + ((t * 16 + g * 4) ^ swz);
        *(f32x4*)lp = nr;
        *(f32x4*)(lp + 512) = ni;
      }
    }
    // GEMM2 B-fragments: lane needs 8 consecutive n of its own b row
    short8v pbr[2], pbi[2];
    #pragma unroll
    for (int bt = 0; bt < 2; ++bt) {
      const float* lp = mylds + bt * 1024 + bl * 32;
      const int w0 = (g * 8) ^ swz;
      const int w1o = (g * 8 + 4) ^ swz;
      f32x4 r0 = *(const f32x4*)(lp + w0);
      f32x4 r1 = *(const f32x4*)(lp + w1o);
      f32x4 i0 = *(const f32x4*)(lp + 512 + w0);
      f32x4 i1 = *(const f32x4*)(lp + 512 + w1o);
      short8v fr, fi;
      fr[0] = (short)f2bf(r0[0]); fr[1] = (short)f2bf(r0[1]);
      fr[2] = (short)f2bf(r0[2]); fr[3] = (short)f2bf(r0[3]);
      fr[4] = (short)f2bf(r1[0]); fr[5] = (short)f2bf(r1[1]);
      fr[6] = (short)f2bf(r1[2]); fr[7] = (short)f2bf(r1[3]);
      fi[0] = (short)f2bf(i0[0]); fi[1] = (short)f2bf(i0[1]);
      fi[2] = (short)f2bf(i0[2]); fi[3] = (short)f2bf(i0[3]);
      fi[4] = (short)f2bf(i1[0]); fi[5] = (short)f2bf(i1[1]);
      fi[6] = (short)f2bf(i1[2]); fi[7] = (short)f2bf(i1[3]);
      pbr[bt] = fr; pbi[bt] = fi;
    }
    // GEMM2 partial over this 32-state chunk
    const unsigned short* w2rb = w2re + (h * HEAD_DIM + bl) * DSTATE + kk * 32 + g * 8;
    const unsigned short* w2ib = w2mi + (h * HEAD_DIM + bl) * DSTATE + kk * 32 + g * 8;
    #pragma unroll
    for (int pt = 0; pt < 8; ++pt) {
      short8v a2r = *(const short8v*)(w2rb + pt * 16 * DSTATE);
      short8v a2i = *(const short8v*)(w2ib + pt * 16 * DSTATE);
      #pragma unroll
      for (int bt = 0; bt < 2; ++bt) {
        acc[pt][bt] = __builtin_amdgcn_mfma_f32_16x16x32_bf16(a2r, pbr[bt], acc[pt][bt], 0, 0, 0);
        acc[pt][bt] = __builtin_amdgcn_mfma_f32_16x16x32_bf16(a2i, pbi[bt], acc[pt][bt], 0, 0, 0);
      }
    }
  }
  // epilogue: out = x_t + 2*Ch + D*x_hat
  #pragma unroll
  for (int pt = 0; pt < 8; ++pt) {
    #pragma unroll
    for (int bt = 0; bt < 2; ++bt) {
      const int b = rowbase + bt * 16 + bl;
      const int col = h * HEAD_DIM + pt * 16 + g * 4;
      const int o = b * DIM + col;
      const f32x4 xt4 = *(const f32x4*)(xt + o);
      const f32x4 d4 = *(const f32x4*)(dvec + col);
      ushort4v xh4 = *(const ushort4v*)(xbf + o);
      f32x4 ro;
      #pragma unroll
      for (int r = 0; r < 4; ++r)
        ro[r] = xt4[r] + 2.0f * acc[pt][bt][r] + d4[r] * bf2f(xh4[r]);
      *(f32x4*)(out + o) = ro;
    }
  }
}

extern "C" void kernel_launch(void* const* d_in, const int* in_sizes, int n_in,
                              void* d_out, int out_size, void* d_ws, size_t ws_size,
                              hipStream_t stream) {
  const float* x_t      = (const float*)d_in[0];
  const float* state_re = (const float*)d_in[1];
  const float* state_im = (const float*)d_in[2];
  const float* norm_w   = (const float*)d_in[3];
  const float* A_re_log = (const float*)d_in[4];
  const float* A_im     = (const float*)d_in[5];
  const float* B_re     = (const float*)d_in[6];
  const float* B_im     = (const float*)d_in[7];
  const float* C_re     = (const float*)d_in[8];
  const float* C_im     = (const float*)d_in[9];
  const float* Dv       = (const float*)d_in[10];
  const float* log_dt   = (const float*)d_in[11];

  float* out   = (float*)d_out;
  float* ns_re = out + (size_t)BATCH * DIM;
  float* ns_im = ns_re + (size_t)BATCH * HEADS * DSTATE;

  char* ws = (char*)d_ws;
  unsigned short* xbf  = (unsigned short*)ws;                       // 16 MB
  unsigned short* w1re = (unsigned short*)(ws + 16777216);          // 512 KB each
  unsigned short* w1im = w1re + 262144;
  unsigned short* w2re = w1im + 262144;
  unsigned short* w2mi = w2re + 262144;
  float* abr = (float*)(ws + 16777216 + 4 * 524288);
  float* abi = abr + 2048;
  float* cre = abi + 2048;
  float* cim = cre + 2048;

  pc_params<<<8, 256, 0, stream>>>(log_dt, A_re_log, A_im, abr, abi, cre, cim);
  pc_w1<<<1024, 256, 0, stream>>>(B_re, B_im, cre, cim, w1re, w1im);
  pc_w2<<<1024, 256, 0, stream>>>(C_re, C_im, w2re, w2mi);
  rms_k<<<2048, 256, 0, stream>>>(x_t, norm_w, xbf);
  s5_main<<<512, 256, 0, stream>>>(xbf, w1re, w1im, w2re, w2mi, abr, abi,
                                   state_re, state_im, x_t, Dv, out, ns_re, ns_im);
}